// Round 1
// baseline (1566.405 us; speedup 1.0000x reference)
//
#include <hip/hip_runtime.h>
#include <hip/hip_bf16.h>
#include <math.h>

#define NH 8
#define DH 32
#define DIM 256
#define SEQ 2048
#define BATCH 4
#define NB 512            // SEQ / C
#define SCALE 0.17677669529663687f  // DH^-0.5

__device__ __forceinline__ float sigmoidf_(float x){ return 1.f/(1.f+__expf(-x)); }

// ---------------- copy (residual stream init) ----------------
__global__ void copy_f32(const float* __restrict__ in, float* __restrict__ out, int n4){
  int i = blockIdx.x*blockDim.x + threadIdx.x;
  if (i < n4) ((float4*)out)[i] = ((const float4*)in)[i];
}

// ---------------- layernorm: one wave per row ----------------
__global__ __launch_bounds__(256) void ln_k(const float* __restrict__ x, const float* __restrict__ g,
                                            const float* __restrict__ b, float* __restrict__ h){
  int row  = blockIdx.x*4 + (threadIdx.x>>6);
  int lane = threadIdx.x & 63;
  int c = lane*4;
  const float* xr = x + (size_t)row*DIM + c;
  float4 v = *(const float4*)xr;
  float s = v.x+v.y+v.z+v.w;
  float q = v.x*v.x+v.y*v.y+v.z*v.z+v.w*v.w;
  #pragma unroll
  for (int off=32; off>0; off>>=1){ s += __shfl_xor(s, off); q += __shfl_xor(q, off); }
  float mean = s * (1.f/DIM);
  float var  = q * (1.f/DIM) - mean*mean;
  float rs = rsqrtf(var + 1e-5f);
  float4 gg = *(const float4*)(g + c);
  float4 bb = *(const float4*)(b + c);
  float4 o;
  o.x = (v.x-mean)*rs*gg.x + bb.x;
  o.y = (v.y-mean)*rs*gg.y + bb.y;
  o.z = (v.z-mean)*rs*gg.z + bb.z;
  o.w = (v.w-mean)*rs*gg.w + bb.w;
  *(float4*)(h + (size_t)row*DIM + c) = o;
}

// ---------------- generic f32 GEMM: C[M,N] = act(A[M,K]@B[K,N] + bias) (+= C) ----------------
// tile 128x64, BK=16, 256 threads, 8x4 per thread
template<bool BIAS, bool LEAKY, bool ACC>
__global__ __launch_bounds__(256) void gemm_f32(const float* __restrict__ A, const float* __restrict__ B,
                                                const float* __restrict__ bias, float* __restrict__ C,
                                                int M, int N, int K){
  __shared__ float As[16][132];   // transposed: As[kk][m], stride 132 (16B-aligned rows)
  __shared__ float Bs[16][68];
  int tid = threadIdx.x;
  int m0 = blockIdx.x*128, n0 = blockIdx.y*64;
  int tx = tid & 15, ty = tid >> 4;
  float acc[8][4];
  #pragma unroll
  for (int i=0;i<8;i++)
    #pragma unroll
    for (int j=0;j<4;j++) acc[i][j]=0.f;
  int ar = tid >> 2;            // 0..63
  int ac = (tid & 3)*4;         // 0,4,8,12
  int bk = tid >> 4;            // 0..15
  int bn = (tid & 15)*4;        // 0..60
  for (int k0=0; k0<K; k0+=16){
    float4 a0 = *(const float4*)(A + (size_t)(m0+ar   )*K + k0+ac);
    float4 a1 = *(const float4*)(A + (size_t)(m0+ar+64)*K + k0+ac);
    As[ac+0][ar]=a0.x; As[ac+1][ar]=a0.y; As[ac+2][ar]=a0.z; As[ac+3][ar]=a0.w;
    As[ac+0][ar+64]=a1.x; As[ac+1][ar+64]=a1.y; As[ac+2][ar+64]=a1.z; As[ac+3][ar+64]=a1.w;
    #pragma unroll
    for (int jj=0;jj<4;jj++){
      int n = n0 + bn + jj;
      Bs[bk][bn+jj] = (n < N) ? B[(size_t)(k0+bk)*N + n] : 0.f;
    }
    __syncthreads();
    #pragma unroll
    for (int kk=0;kk<16;kk++){
      float4 bv  = *(const float4*)&Bs[kk][tx*4];
      float4 av0 = *(const float4*)&As[kk][ty*8];
      float4 av1 = *(const float4*)&As[kk][ty*8+4];
      float av[8] = {av0.x,av0.y,av0.z,av0.w,av1.x,av1.y,av1.z,av1.w};
      float bw[4] = {bv.x,bv.y,bv.z,bv.w};
      #pragma unroll
      for (int i=0;i<8;i++)
        #pragma unroll
        for (int j=0;j<4;j++) acc[i][j] += av[i]*bw[j];
    }
    __syncthreads();
  }
  #pragma unroll
  for (int i=0;i<8;i++){
    int m = m0 + ty*8 + i;
    #pragma unroll
    for (int j=0;j<4;j++){
      int n = n0 + tx*4 + j;
      if (n < N){
        float val = acc[i][j];
        if (BIAS)  val += bias[n];
        if (LEAKY) val = val > 0.f ? val : 0.01f*val;
        float* cp = C + (size_t)m*N + n;
        if (ACC) val += *cp;
        *cp = val;
      }
    }
  }
}

// ---------------- mean-pool K/V blocks (C=4) ----------------
__global__ void pool_k(const float* __restrict__ k, const float* __restrict__ v,
                       float* __restrict__ kc, float* __restrict__ vc){
  int i = blockIdx.x*256 + threadIdx.x;       // 0 .. B*NB*DIM-1
  if (i >= BATCH*NB*DIM) return;
  int c = i & 255, n = (i >> 8) & 511, b = i >> 17;
  size_t base = (((size_t)b*SEQ + n*4)*DIM) + c;
  kc[i] = 0.25f*(k[base] + k[base+DIM] + k[base+2*DIM] + k[base+3*DIM]);
  vc[i] = 0.25f*(v[base] + v[base+DIM] + v[base+2*DIM] + v[base+3*DIM]);
}

// ---------------- fused NSA attention ----------------
// grid = B*H*8 blocks; block j of (b,h) runs waves W_perm = {j, 8+j, 16+j, 24+j},
// wave handles t in [W_perm*64, W_perm*64+64)  -> balanced nvis across blocks.
__global__ __launch_bounds__(256) void nsa_attn(
    const float* __restrict__ q, const float* __restrict__ k, const float* __restrict__ v,
    const float* __restrict__ kc, const float* __restrict__ vc,
    const float* __restrict__ g, float* __restrict__ o)
{
  __shared__ float kcs[NB*DH];   // 64 KiB
  __shared__ float vcs[NB*DH];   // 64 KiB
  int blk = blockIdx.x;
  int j = blk & 7, bh = blk >> 3;
  int hh = bh & 7, b = bh >> 3;
  int tid = threadIdx.x;
  int nvmax = (25 + j) * 16;     // max visible compressed blocks needed by this block
  const float* kcg = kc + ((size_t)b*NB)*DIM + hh*DH;
  const float* vcg = vc + ((size_t)b*NB)*DIM + hh*DH;
  for (int base = tid; base < nvmax*8; base += 256){
    int n = base >> 3, p = (base & 7)*4;
    *(float4*)&kcs[n*DH + p] = *(const float4*)(kcg + (size_t)n*DIM + p);
    *(float4*)&vcs[n*DH + p] = *(const float4*)(vcg + (size_t)n*DIM + p);
  }
  __syncthreads();
  int w = tid >> 6, lane = tid & 63;
  int t = ((w<<3)+j)*64 + lane;
  size_t rowq = ((size_t)b*SEQ + t)*DIM + hh*DH;
  float qv[32];
  #pragma unroll
  for (int d=0; d<32; d+=4){
    float4 t4 = *(const float4*)(q + rowq + d);
    qv[d]=t4.x; qv[d+1]=t4.y; qv[d+2]=t4.z; qv[d+3]=t4.w;
  }
  int own = t >> 2, nvis = (t+1) >> 2;
  // ---- compressed branch (max-free softmax: |s|<~0.3, exp cannot overflow) + argmax tracking
  float l = 0.f, best = -1e30f;
  int bestn = (own==0) ? 1 : 0;  // jax top_k fallback when no visible non-own block
  float acc[32];
  #pragma unroll
  for (int d=0;d<32;d++) acc[d]=0.f;
  for (int n=0; n<nvis; ++n){
    float s = 0.f;
    #pragma unroll
    for (int d=0; d<32; d+=4){
      float4 kv = *(const float4*)&kcs[n*DH + d];
      s += qv[d]*kv.x + qv[d+1]*kv.y + qv[d+2]*kv.z + qv[d+3]*kv.w;
    }
    s *= SCALE;
    if (n != own && s > best){ best = s; bestn = n; }  // strict > == lowest-index tie-break
    float p = __expf(s);
    l += p;
    #pragma unroll
    for (int d=0; d<32; d+=4){
      float4 vv = *(const float4*)&vcs[n*DH + d];
      acc[d]   += p*vv.x; acc[d+1] += p*vv.y;
      acc[d+2] += p*vv.z; acc[d+3] += p*vv.w;
    }
  }
  const float* gr = g + ((size_t)b*SEQ + t)*24 + hh;
  float g0 = sigmoidf_(gr[0]), g1 = sigmoidf_(gr[8]), g2 = sigmoidf_(gr[16]);
  float out[32];
  float inv = (nvis > 0) ? g0/l : 0.f;
  #pragma unroll
  for (int d=0;d<32;d++) out[d] = acc[d]*inv;

  // ---- selection branch: own block + best block, causal token mask
  float s2[8];
  float m2 = -1e30f;
  #pragma unroll
  for (int ki=0; ki<8; ++ki){
    int tt = (ki<4 ? own : bestn)*4 + (ki&3);
    float s = -1e30f;
    if (tt <= t){
      const float* kr = k + ((size_t)b*SEQ + tt)*DIM + hh*DH;
      float sv = 0.f;
      #pragma unroll
      for (int d=0; d<32; d+=4){
        float4 kv = *(const float4*)(kr + d);
        sv += qv[d]*kv.x + qv[d+1]*kv.y + qv[d+2]*kv.z + qv[d+3]*kv.w;
      }
      s = sv*SCALE;
      m2 = fmaxf(m2, s);
    }
    s2[ki] = s;
  }
  float l2 = 0.f;
  float acc2[32];
  #pragma unroll
  for (int d=0;d<32;d++) acc2[d]=0.f;
  #pragma unroll
  for (int ki=0; ki<8; ++ki){
    int tt = (ki<4 ? own : bestn)*4 + (ki&3);
    if (tt <= t){
      float p = __expf(s2[ki] - m2);
      l2 += p;
      const float* vr = v + ((size_t)b*SEQ + tt)*DIM + hh*DH;
      #pragma unroll
      for (int d=0; d<32; d+=4){
        float4 vv = *(const float4*)(vr + d);
        acc2[d]   += p*vv.x; acc2[d+1] += p*vv.y;
        acc2[d+2] += p*vv.z; acc2[d+3] += p*vv.w;
      }
    }
  }
  float inv2 = g1/l2;   // l2 >= 1 (self token always visible)
  #pragma unroll
  for (int d=0;d<32;d++) out[d] += acc2[d]*inv2;

  // ---- sliding window (W=2): tokens t-1, t
  int tp = (t>0) ? t-1 : 0;
  const float* ka = k + ((size_t)b*SEQ + tp)*DIM + hh*DH;
  const float* kb2= k + ((size_t)b*SEQ + t )*DIM + hh*DH;
  float sa=0.f, sb=0.f;
  #pragma unroll
  for (int d=0; d<32; d+=4){
    float4 k1 = *(const float4*)(ka + d);
    float4 k2 = *(const float4*)(kb2 + d);
    sa += qv[d]*k1.x + qv[d+1]*k1.y + qv[d+2]*k1.z + qv[d+3]*k1.w;
    sb += qv[d]*k2.x + qv[d+1]*k2.y + qv[d+2]*k2.z + qv[d+3]*k2.w;
  }
  sa *= SCALE; sb *= SCALE;
  float m3 = (t>0) ? fmaxf(sa, sb) : sb;
  float pa = (t>0) ? __expf(sa-m3) : 0.f;
  float pb = __expf(sb-m3);
  float inv3 = g2/(pa+pb);
  const float* va = v + ((size_t)b*SEQ + tp)*DIM + hh*DH;
  const float* vb = v + ((size_t)b*SEQ + t )*DIM + hh*DH;
  float* orow = o + ((size_t)b*SEQ + t)*DIM + hh*DH;
  #pragma unroll
  for (int d=0; d<32; d+=4){
    float4 a4 = *(const float4*)(va+d);
    float4 b4 = *(const float4*)(vb+d);
    float4 r;
    r.x = out[d]   + (pa*a4.x + pb*b4.x)*inv3;
    r.y = out[d+1] + (pa*a4.y + pb*b4.y)*inv3;
    r.z = out[d+2] + (pa*a4.z + pb*b4.z)*inv3;
    r.w = out[d+3] + (pa*a4.w + pb*b4.w)*inv3;
    *(float4*)(orow+d) = r;
  }
}

extern "C" void kernel_launch(void* const* d_in, const int* in_sizes, int n_in,
                              void* d_out, int out_size, void* d_ws, size_t ws_size,
                              hipStream_t stream) {
  const float* x_in   = (const float*)d_in[0];
  const float* ln_a_g = (const float*)d_in[1];
  const float* ln_a_b = (const float*)d_in[2];
  const float* Wq     = (const float*)d_in[3];
  const float* Wk     = (const float*)d_in[4];
  const float* Wv     = (const float*)d_in[5];
  const float* Wg     = (const float*)d_in[6];
  const float* Wo     = (const float*)d_in[7];
  const float* ln_f_g = (const float*)d_in[8];
  const float* ln_f_b = (const float*)d_in[9];
  const float* W1     = (const float*)d_in[10];
  const float* b1     = (const float*)d_in[11];
  const float* W2     = (const float*)d_in[12];
  const float* b2     = (const float*)d_in[13];

  float* xout = (float*)d_out;             // running residual stream [8192][256]
  float* ws = (float*)d_ws;
  const size_t NTOK = (size_t)BATCH*SEQ;   // 8192
  float* h   = ws;                          // [8192][256]
  float* qb  = h   + NTOK*DIM;
  float* kb  = qb  + NTOK*DIM;
  float* vb  = kb  + NTOK*DIM;
  float* gb  = vb  + NTOK*DIM;              // [8192][24]
  float* kcb = gb  + NTOK*24;               // [4][512][256]
  float* vcb = kcb + (size_t)BATCH*NB*DIM;
  float* ob  = vcb + (size_t)BATCH*NB*DIM;  // [8192][256]
  float* mid = ob  + NTOK*DIM;              // [8192][512]

  copy_f32<<<2048, 256, 0, stream>>>(x_in, xout, (int)(NTOK*DIM/4));

  dim3 g4(64,4), g8(64,8), g1(64,1);
  for (int i=0;i<4;i++){
    ln_k<<<2048,256,0,stream>>>(xout, ln_a_g + i*DIM, ln_a_b + i*DIM, h);
    gemm_f32<false,false,false><<<g4,256,0,stream>>>(h, Wq + (size_t)i*DIM*DIM, nullptr, qb, 8192,256,256);
    gemm_f32<false,false,false><<<g4,256,0,stream>>>(h, Wk + (size_t)i*DIM*DIM, nullptr, kb, 8192,256,256);
    gemm_f32<false,false,false><<<g4,256,0,stream>>>(h, Wv + (size_t)i*DIM*DIM, nullptr, vb, 8192,256,256);
    gemm_f32<false,false,false><<<g1,256,0,stream>>>(h, Wg + (size_t)i*DIM*24,  nullptr, gb, 8192,24,256);
    pool_k<<<2048,256,0,stream>>>(kb, vb, kcb, vcb);
    nsa_attn<<<256,256,0,stream>>>(qb, kb, vb, kcb, vcb, gb, ob);
    gemm_f32<false,false,true><<<g4,256,0,stream>>>(ob, Wo + (size_t)i*DIM*DIM, nullptr, xout, 8192,256,256);
    if (i & 1){
      int l = i >> 1;
      ln_k<<<2048,256,0,stream>>>(xout, ln_f_g + l*DIM, ln_f_b + l*DIM, h);
      gemm_f32<true,true,false><<<g8,256,0,stream>>>(h,   W1 + (size_t)l*DIM*512, b1 + l*512, mid,  8192,512,256);
      gemm_f32<true,false,true><<<g4,256,0,stream>>>(mid, W2 + (size_t)l*512*DIM, b2 + l*DIM, xout, 8192,256,512);
    }
  }
}

// Round 2
// 1308.399 us; speedup vs baseline: 1.1972x; 1.1972x over previous
//
#include <hip/hip_runtime.h>
#include <hip/hip_bf16.h>
#include <math.h>

#define NH 8
#define DH 32
#define DIM 256
#define SEQ 2048
#define BATCH 4
#define NB 512            // SEQ / C
#define SCALE 0.17677669529663687f  // DH^-0.5

__device__ __forceinline__ float sigmoidf_(float x){ return 1.f/(1.f+__expf(-x)); }

// ---------------- copy (residual stream init) ----------------
__global__ void copy_f32(const float* __restrict__ in, float* __restrict__ out, int n4){
  int i = blockIdx.x*blockDim.x + threadIdx.x;
  if (i < n4) ((float4*)out)[i] = ((const float4*)in)[i];
}

// ---------------- layernorm: one wave per row ----------------
__global__ __launch_bounds__(256) void ln_k(const float* __restrict__ x, const float* __restrict__ g,
                                            const float* __restrict__ b, float* __restrict__ h){
  int row  = blockIdx.x*4 + (threadIdx.x>>6);
  int lane = threadIdx.x & 63;
  int c = lane*4;
  const float* xr = x + (size_t)row*DIM + c;
  float4 v = *(const float4*)xr;
  float s = v.x+v.y+v.z+v.w;
  float q = v.x*v.x+v.y*v.y+v.z*v.z+v.w*v.w;
  #pragma unroll
  for (int off=32; off>0; off>>=1){ s += __shfl_xor(s, off); q += __shfl_xor(q, off); }
  float mean = s * (1.f/DIM);
  float var  = q * (1.f/DIM) - mean*mean;
  float rs = rsqrtf(var + 1e-5f);
  float4 gg = *(const float4*)(g + c);
  float4 bb = *(const float4*)(b + c);
  float4 o;
  o.x = (v.x-mean)*rs*gg.x + bb.x;
  o.y = (v.y-mean)*rs*gg.y + bb.y;
  o.z = (v.z-mean)*rs*gg.z + bb.z;
  o.w = (v.w-mean)*rs*gg.w + bb.w;
  *(float4*)(h + (size_t)row*DIM + c) = o;
}

// ---------------- generic f32 GEMM: C[M,N] = act(A[M,K]@B[K,N] + bias) (+= C) ----------------
// tile 128x64, BK=16, 256 threads, 8x4 per thread
template<bool BIAS, bool LEAKY, bool ACC>
__global__ __launch_bounds__(256) void gemm_f32(const float* __restrict__ A, const float* __restrict__ B,
                                                const float* __restrict__ bias, float* __restrict__ C,
                                                int M, int N, int K){
  __shared__ float As[16][132];   // transposed: As[kk][m], stride 132 (16B-aligned rows)
  __shared__ float Bs[16][68];
  int tid = threadIdx.x;
  int m0 = blockIdx.x*128, n0 = blockIdx.y*64;
  int tx = tid & 15, ty = tid >> 4;
  float acc[8][4];
  #pragma unroll
  for (int i=0;i<8;i++)
    #pragma unroll
    for (int j=0;j<4;j++) acc[i][j]=0.f;
  int ar = tid >> 2;            // 0..63
  int ac = (tid & 3)*4;         // 0,4,8,12
  int bk = tid >> 4;            // 0..15
  int bn = (tid & 15)*4;        // 0..60
  for (int k0=0; k0<K; k0+=16){
    float4 a0 = *(const float4*)(A + (size_t)(m0+ar   )*K + k0+ac);
    float4 a1 = *(const float4*)(A + (size_t)(m0+ar+64)*K + k0+ac);
    As[ac+0][ar]=a0.x; As[ac+1][ar]=a0.y; As[ac+2][ar]=a0.z; As[ac+3][ar]=a0.w;
    As[ac+0][ar+64]=a1.x; As[ac+1][ar+64]=a1.y; As[ac+2][ar+64]=a1.z; As[ac+3][ar+64]=a1.w;
    #pragma unroll
    for (int jj=0;jj<4;jj++){
      int n = n0 + bn + jj;
      Bs[bk][bn+jj] = (n < N) ? B[(size_t)(k0+bk)*N + n] : 0.f;
    }
    __syncthreads();
    #pragma unroll
    for (int kk=0;kk<16;kk++){
      float4 bv  = *(const float4*)&Bs[kk][tx*4];
      float4 av0 = *(const float4*)&As[kk][ty*8];
      float4 av1 = *(const float4*)&As[kk][ty*8+4];
      float av[8] = {av0.x,av0.y,av0.z,av0.w,av1.x,av1.y,av1.z,av1.w};
      float bw[4] = {bv.x,bv.y,bv.z,bv.w};
      #pragma unroll
      for (int i=0;i<8;i++)
        #pragma unroll
        for (int j=0;j<4;j++) acc[i][j] += av[i]*bw[j];
    }
    __syncthreads();
  }
  #pragma unroll
  for (int i=0;i<8;i++){
    int m = m0 + ty*8 + i;
    #pragma unroll
    for (int j=0;j<4;j++){
      int n = n0 + tx*4 + j;
      if (n < N){
        float val = acc[i][j];
        if (BIAS)  val += bias[n];
        if (LEAKY) val = val > 0.f ? val : 0.01f*val;
        float* cp = C + (size_t)m*N + n;
        if (ACC) val += *cp;
        *cp = val;
      }
    }
  }
}

// ---------------- mean-pool K/V blocks (C=4) ----------------
__global__ void pool_k(const float* __restrict__ k, const float* __restrict__ v,
                       float* __restrict__ kc, float* __restrict__ vc){
  int i = blockIdx.x*256 + threadIdx.x;       // 0 .. B*NB*DIM-1
  if (i >= BATCH*NB*DIM) return;
  int c = i & 255, n = (i >> 8) & 511, b = i >> 17;
  size_t base = (((size_t)b*SEQ + n*4)*DIM) + c;
  kc[i] = 0.25f*(k[base] + k[base+DIM] + k[base+2*DIM] + k[base+3*DIM]);
  vc[i] = 0.25f*(v[base] + v[base+DIM] + v[base+2*DIM] + v[base+3*DIM]);
}

// ---------------- fused NSA attention, split-n version ----------------
// grid = 1024 blocks: block e -> token group g = 31 - e/32 (heavy first), (b,h) = e%32.
// Block owns 64 tokens; wave w computes compressed-branch partials over the
// n-range quarter [w*chunk, (w+1)*chunk); partials (acc,l,best,bestn) combine
// linearly (max-free softmax) in LDS; wave w then finalizes tokens [16w,16w+16)
// (selection + sliding window + gated store).
__global__ __launch_bounds__(256, 4) void nsa_attn(
    const float* __restrict__ q, const float* __restrict__ k, const float* __restrict__ v,
    const float* __restrict__ kc, const float* __restrict__ vc,
    const float* __restrict__ g, float* __restrict__ o)
{
  __shared__ float red[4*64*36];   // 36 KiB: [split][token][32 acc + l + best + bestn + pad]
  int e = blockIdx.x;
  int gidx = 31 - (e >> 5);        // token group, heavy groups dispatched first
  int bh = e & 31;
  int hh = bh & 7, b = bh >> 3;
  int tid = threadIdx.x;
  int w = __builtin_amdgcn_readfirstlane(tid >> 6);   // wave id, provably uniform
  int lane = tid & 63;
  int t = gidx*64 + lane;
  const float* kcg = kc + ((size_t)b*NB)*DIM + hh*DH;
  const float* vcg = vc + ((size_t)b*NB)*DIM + hh*DH;

  // q for this lane's token (all 4 waves hold all 64 tokens' q)
  size_t rowq = ((size_t)b*SEQ + t)*DIM + hh*DH;
  float qv[32];
  #pragma unroll
  for (int d=0; d<32; d+=4){
    float4 t4 = *(const float4*)(q + rowq + d);
    qv[d]=t4.x; qv[d+1]=t4.y; qv[d+2]=t4.z; qv[d+3]=t4.w;
  }
  int own = t >> 2, nvis = (t+1) >> 2;

  // ---- phase 1: compressed-branch partial over this wave's n-quarter
  int chunk = 4*(gidx+1);          // nvis_max/4 = (16*gidx+16)/4
  int n0 = w*chunk, n1 = n0 + chunk;
  float l = 0.f, best = -1e30f;
  int bestn = -1;
  float acc[32];
  #pragma unroll
  for (int d=0;d<32;d++) acc[d]=0.f;
  for (int n=n0; n<n1; ++n){
    const float* kp = kcg + (size_t)n*DIM;    // wave-uniform address
    float s = 0.f;
    #pragma unroll
    for (int d=0; d<32; d+=4){
      float4 kv = *(const float4*)(kp + d);
      s += qv[d]*kv.x + qv[d+1]*kv.y + qv[d+2]*kv.z + qv[d+3]*kv.w;
    }
    s *= SCALE;
    bool act = (n < nvis);
    if (act && n != own && s > best){ best = s; bestn = n; }  // strict > = lowest-index tie-break
    float p = act ? __expf(s) : 0.f;          // max-free: |s| small, exp safe
    l += p;
    const float* vp = vcg + (size_t)n*DIM;    // wave-uniform address
    #pragma unroll
    for (int d=0; d<32; d+=4){
      float4 vv = *(const float4*)(vp + d);
      acc[d]   += p*vv.x; acc[d+1] += p*vv.y;
      acc[d+2] += p*vv.z; acc[d+3] += p*vv.w;
    }
  }
  // write partials: stride 36 floats (144 B) -> 2-way bank alias only (free)
  float4* myr = (float4*)&red[(w*64 + lane)*36];
  #pragma unroll
  for (int d=0; d<8; d++) myr[d] = make_float4(acc[d*4],acc[d*4+1],acc[d*4+2],acc[d*4+3]);
  myr[8] = make_float4(l, best, __int_as_float(bestn), 0.f);
  __syncthreads();

  // ---- phase 2: wave w finalizes tokens [16w, 16w+16) (lane == local token idx)
  if ((lane >> 4) != w) return;

  float ll = 0.f, bb = -1e30f;
  int bn = (own==0) ? 1 : 0;       // jax top_k fallback when no visible non-own block
  float out[32];
  #pragma unroll
  for (int d=0;d<32;d++) out[d]=0.f;
  #pragma unroll
  for (int sp=0; sp<4; ++sp){      // ascending split = ascending n: tie-break preserved
    const float4* r = (const float4*)&red[(sp*64 + lane)*36];
    #pragma unroll
    for (int d=0; d<8; d++){
      float4 a4 = r[d];
      out[d*4]+=a4.x; out[d*4+1]+=a4.y; out[d*4+2]+=a4.z; out[d*4+3]+=a4.w;
    }
    float4 m4 = r[8];
    ll += m4.x;
    if (m4.y > bb){ bb = m4.y; bn = __float_as_int(m4.z); }
  }
  const float* gr = g + ((size_t)b*SEQ + t)*24 + hh;
  float g0 = sigmoidf_(gr[0]), g1 = sigmoidf_(gr[8]), g2 = sigmoidf_(gr[16]);
  float inv = (nvis > 0) ? g0/ll : 0.f;
  #pragma unroll
  for (int d=0;d<32;d++) out[d] *= inv;

  // ---- selection branch: own block + best block, causal token mask
  float s2[8];
  float m2 = -1e30f;
  #pragma unroll
  for (int ki=0; ki<8; ++ki){
    int tt = (ki<4 ? own : bn)*4 + (ki&3);
    float s = -1e30f;
    if (tt <= t){
      const float* kr = k + ((size_t)b*SEQ + tt)*DIM + hh*DH;
      float sv = 0.f;
      #pragma unroll
      for (int d=0; d<32; d+=4){
        float4 kv = *(const float4*)(kr + d);
        sv += qv[d]*kv.x + qv[d+1]*kv.y + qv[d+2]*kv.z + qv[d+3]*kv.w;
      }
      s = sv*SCALE;
      m2 = fmaxf(m2, s);
    }
    s2[ki] = s;
  }
  float l2 = 0.f;
  #pragma unroll
  for (int ki=0; ki<8; ++ki)
    if (s2[ki] > -1e29f) l2 += __expf(s2[ki] - m2);
  float inv2 = g1/l2;              // l2 >= 1 (self token always visible)
  #pragma unroll
  for (int ki=0; ki<8; ++ki){
    int tt = (ki<4 ? own : bn)*4 + (ki&3);
    if (tt <= t){
      float pw = __expf(s2[ki] - m2) * inv2;
      const float* vr = v + ((size_t)b*SEQ + tt)*DIM + hh*DH;
      #pragma unroll
      for (int d=0; d<32; d+=4){
        float4 vv = *(const float4*)(vr + d);
        out[d]   += pw*vv.x; out[d+1] += pw*vv.y;
        out[d+2] += pw*vv.z; out[d+3] += pw*vv.w;
      }
    }
  }

  // ---- sliding window (W=2): tokens t-1, t
  int tp = (t>0) ? t-1 : 0;
  const float* ka = k + ((size_t)b*SEQ + tp)*DIM + hh*DH;
  const float* kb2= k + ((size_t)b*SEQ + t )*DIM + hh*DH;
  float sa=0.f, sb=0.f;
  #pragma unroll
  for (int d=0; d<32; d+=4){
    float4 k1 = *(const float4*)(ka + d);
    float4 k2 = *(const float4*)(kb2 + d);
    sa += qv[d]*k1.x + qv[d+1]*k1.y + qv[d+2]*k1.z + qv[d+3]*k1.w;
    sb += qv[d]*k2.x + qv[d+1]*k2.y + qv[d+2]*k2.z + qv[d+3]*k2.w;
  }
  sa *= SCALE; sb *= SCALE;
  float m3 = (t>0) ? fmaxf(sa, sb) : sb;
  float pa = (t>0) ? __expf(sa-m3) : 0.f;
  float pb = __expf(sb-m3);
  float inv3 = g2/(pa+pb);
  const float* va = v + ((size_t)b*SEQ + tp)*DIM + hh*DH;
  const float* vb = v + ((size_t)b*SEQ + t )*DIM + hh*DH;
  float* orow = o + ((size_t)b*SEQ + t)*DIM + hh*DH;
  #pragma unroll
  for (int d=0; d<32; d+=4){
    float4 a4 = *(const float4*)(va+d);
    float4 b4 = *(const float4*)(vb+d);
    float4 r;
    r.x = out[d]   + (pa*a4.x + pb*b4.x)*inv3;
    r.y = out[d+1] + (pa*a4.y + pb*b4.y)*inv3;
    r.z = out[d+2] + (pa*a4.z + pb*b4.z)*inv3;
    r.w = out[d+3] + (pa*a4.w + pb*b4.w)*inv3;
    *(float4*)(orow+d) = r;
  }
}

extern "C" void kernel_launch(void* const* d_in, const int* in_sizes, int n_in,
                              void* d_out, int out_size, void* d_ws, size_t ws_size,
                              hipStream_t stream) {
  const float* x_in   = (const float*)d_in[0];
  const float* ln_a_g = (const float*)d_in[1];
  const float* ln_a_b = (const float*)d_in[2];
  const float* Wq     = (const float*)d_in[3];
  const float* Wk     = (const float*)d_in[4];
  const float* Wv     = (const float*)d_in[5];
  const float* Wg     = (const float*)d_in[6];
  const float* Wo     = (const float*)d_in[7];
  const float* ln_f_g = (const float*)d_in[8];
  const float* ln_f_b = (const float*)d_in[9];
  const float* W1     = (const float*)d_in[10];
  const float* b1     = (const float*)d_in[11];
  const float* W2     = (const float*)d_in[12];
  const float* b2     = (const float*)d_in[13];

  float* xout = (float*)d_out;             // running residual stream [8192][256]
  float* ws = (float*)d_ws;
  const size_t NTOK = (size_t)BATCH*SEQ;   // 8192
  float* h   = ws;                          // [8192][256]
  float* qb  = h   + NTOK*DIM;
  float* kb  = qb  + NTOK*DIM;
  float* vb  = kb  + NTOK*DIM;
  float* gb  = vb  + NTOK*DIM;              // [8192][24]
  float* kcb = gb  + NTOK*24;               // [4][512][256]
  float* vcb = kcb + (size_t)BATCH*NB*DIM;
  float* ob  = vcb + (size_t)BATCH*NB*DIM;  // [8192][256]
  float* mid = ob  + NTOK*DIM;              // [8192][512]

  copy_f32<<<2048, 256, 0, stream>>>(x_in, xout, (int)(NTOK*DIM/4));

  dim3 g4(64,4), g8(64,8), g1(64,1);
  for (int i=0;i<4;i++){
    ln_k<<<2048,256,0,stream>>>(xout, ln_a_g + i*DIM, ln_a_b + i*DIM, h);
    gemm_f32<false,false,false><<<g4,256,0,stream>>>(h, Wq + (size_t)i*DIM*DIM, nullptr, qb, 8192,256,256);
    gemm_f32<false,false,false><<<g4,256,0,stream>>>(h, Wk + (size_t)i*DIM*DIM, nullptr, kb, 8192,256,256);
    gemm_f32<false,false,false><<<g4,256,0,stream>>>(h, Wv + (size_t)i*DIM*DIM, nullptr, vb, 8192,256,256);
    gemm_f32<false,false,false><<<g1,256,0,stream>>>(h, Wg + (size_t)i*DIM*24,  nullptr, gb, 8192,24,256);
    pool_k<<<2048,256,0,stream>>>(kb, vb, kcb, vcb);
    nsa_attn<<<1024,256,0,stream>>>(qb, kb, vb, kcb, vcb, gb, ob);
    gemm_f32<false,false,true><<<g4,256,0,stream>>>(ob, Wo + (size_t)i*DIM*DIM, nullptr, xout, 8192,256,256);
    if (i & 1){
      int l = i >> 1;
      ln_k<<<2048,256,0,stream>>>(xout, ln_f_g + l*DIM, ln_f_b + l*DIM, h);
      gemm_f32<true,true,false><<<g8,256,0,stream>>>(h,   W1 + (size_t)l*DIM*512, b1 + l*512, mid,  8192,512,256);
      gemm_f32<true,false,true><<<g4,256,0,stream>>>(mid, W2 + (size_t)l*512*DIM, b2 + l*DIM, xout, 8192,256,512);
    }
  }
}

// Round 3
// 903.341 us; speedup vs baseline: 1.7340x; 1.4484x over previous
//
#include <hip/hip_runtime.h>
#include <hip/hip_bf16.h>
#include <math.h>

#define NH 8
#define DH 32
#define DIM 256
#define SEQ 2048
#define BATCH 4
#define NB 512            // SEQ / C
#define QKVS 832          // packed qkvg row stride: 256 q | 256 k | 256 v | 24 g | 40 pad
#define SCALE 0.17677669529663687f  // DH^-0.5

__device__ __forceinline__ float sigmoidf_(float x){ return 1.f/(1.f+__expf(-x)); }

// ---------------- copy (residual stream init) ----------------
__global__ void copy_f32(const float* __restrict__ in, float* __restrict__ out, int n4){
  int i = blockIdx.x*blockDim.x + threadIdx.x;
  if (i < n4) ((float4*)out)[i] = ((const float4*)in)[i];
}

// ---------------- build packed weight [4][256][832] = Wq|Wk|Wv|Wg|0-pad ----------------
__global__ void build_wcat(const float* __restrict__ Wq, const float* __restrict__ Wk,
                           const float* __restrict__ Wv, const float* __restrict__ Wg,
                           float* __restrict__ Wcat){
  int i = blockIdx.x*256 + threadIdx.x;
  if (i >= 4*256*QKVS) return;
  int col = i % QKVS;
  int rk  = (i / QKVS) & 255;
  int l   = i / (QKVS*256);
  float val = 0.f;
  if      (col < 256) val = Wq[((size_t)l*256 + rk)*256 + col];
  else if (col < 512) val = Wk[((size_t)l*256 + rk)*256 + col-256];
  else if (col < 768) val = Wv[((size_t)l*256 + rk)*256 + col-512];
  else if (col < 792) val = Wg[((size_t)l*256 + rk)*24  + col-768];
  Wcat[i] = val;
}

// ---------------- layernorm: one wave per row ----------------
__global__ __launch_bounds__(256) void ln_k(const float* __restrict__ x, const float* __restrict__ g,
                                            const float* __restrict__ b, float* __restrict__ h){
  int row  = blockIdx.x*4 + (threadIdx.x>>6);
  int lane = threadIdx.x & 63;
  int c = lane*4;
  const float* xr = x + (size_t)row*DIM + c;
  float4 v = *(const float4*)xr;
  float s = v.x+v.y+v.z+v.w;
  float q = v.x*v.x+v.y*v.y+v.z*v.z+v.w*v.w;
  #pragma unroll
  for (int off=32; off>0; off>>=1){ s += __shfl_xor(s, off); q += __shfl_xor(q, off); }
  float mean = s * (1.f/DIM);
  float var  = q * (1.f/DIM) - mean*mean;
  float rs = rsqrtf(var + 1e-5f);
  float4 gg = *(const float4*)(g + c);
  float4 bb = *(const float4*)(b + c);
  float4 o;
  o.x = (v.x-mean)*rs*gg.x + bb.x;
  o.y = (v.y-mean)*rs*gg.y + bb.y;
  o.z = (v.z-mean)*rs*gg.z + bb.z;
  o.w = (v.w-mean)*rs*gg.w + bb.w;
  *(float4*)(h + (size_t)row*DIM + c) = o;
}

// ---------------- f32 GEMM, guard-free (M%128==0, N%64==0, K%16==0) ----------------
// tile 128x64, BK=16, 256 threads, 8x4 per thread, register-prefetch double buffer
template<bool BIAS, bool LEAKY, bool ACC>
__global__ __launch_bounds__(256) void gemm_f32(const float* __restrict__ A, const float* __restrict__ B,
                                                const float* __restrict__ bias, float* __restrict__ C,
                                                int M, int N, int K){
  __shared__ float As[16][132];   // transposed: As[kk][m]
  __shared__ float Bs[16][68];
  int tid = threadIdx.x;
  int m0 = blockIdx.x*128, n0 = blockIdx.y*64;
  int tx = tid & 15, ty = tid >> 4;
  int ar = tid >> 2;            // 0..63
  int ac = (tid & 3)*4;         // 0,4,8,12
  int bk = tid >> 4;            // 0..15
  int bn = (tid & 15)*4;        // 0..60
  const float* Ap0 = A + (size_t)(m0+ar)*K + ac;
  const float* Ap1 = Ap0 + (size_t)64*K;
  const float* Bp  = B + (size_t)bk*N + n0 + bn;
  float4 a0 = *(const float4*)Ap0;
  float4 a1 = *(const float4*)Ap1;
  float4 b0 = *(const float4*)Bp;
  float acc[8][4];
  #pragma unroll
  for (int i=0;i<8;i++)
    #pragma unroll
    for (int j=0;j<4;j++) acc[i][j]=0.f;
  for (int k0=0; k0<K; k0+=16){
    As[ac+0][ar]=a0.x; As[ac+1][ar]=a0.y; As[ac+2][ar]=a0.z; As[ac+3][ar]=a0.w;
    As[ac+0][ar+64]=a1.x; As[ac+1][ar+64]=a1.y; As[ac+2][ar+64]=a1.z; As[ac+3][ar+64]=a1.w;
    *(float4*)&Bs[bk][bn] = b0;
    __syncthreads();
    if (k0 + 16 < K){                       // prefetch next K-tile while computing
      a0 = *(const float4*)(Ap0 + k0 + 16);
      a1 = *(const float4*)(Ap1 + k0 + 16);
      b0 = *(const float4*)(Bp + (size_t)(k0+16)*N);
    }
    #pragma unroll
    for (int kk=0;kk<16;kk++){
      float4 bv  = *(const float4*)&Bs[kk][tx*4];
      float4 av0 = *(const float4*)&As[kk][ty*8];
      float4 av1 = *(const float4*)&As[kk][ty*8+4];
      float av[8] = {av0.x,av0.y,av0.z,av0.w,av1.x,av1.y,av1.z,av1.w};
      float bw[4] = {bv.x,bv.y,bv.z,bv.w};
      #pragma unroll
      for (int i=0;i<8;i++)
        #pragma unroll
        for (int j=0;j<4;j++) acc[i][j] += av[i]*bw[j];
    }
    __syncthreads();
  }
  #pragma unroll
  for (int i=0;i<8;i++){
    int m = m0 + ty*8 + i;
    #pragma unroll
    for (int j=0;j<4;j++){
      int n = n0 + tx*4 + j;
      float val = acc[i][j];
      if (BIAS)  val += bias[n];
      if (LEAKY) val = val > 0.f ? val : 0.01f*val;
      float* cp = C + (size_t)m*N + n;
      if (ACC) val += *cp;
      *cp = val;
    }
  }
}

// ---------------- mean-pool K/V blocks (C=4), output [b][h][n][32] ----------------
__global__ void pool_k(const float* __restrict__ qkv, float* __restrict__ kc, float* __restrict__ vc){
  int i = blockIdx.x*256 + threadIdx.x;       // 0 .. B*H*NB*32-1
  if (i >= BATCH*NH*NB*DH) return;
  int d = i & 31, n = (i >> 5) & 511, h = (i >> 14) & 7, b = i >> 17;
  size_t base = ((size_t)(b*SEQ + n*4))*QKVS + 256 + h*DH + d;   // k section
  kc[i] = 0.25f*(qkv[base] + qkv[base+QKVS] + qkv[base+2*QKVS] + qkv[base+3*QKVS]);
  base += 256;                                                    // v section
  vc[i] = 0.25f*(qkv[base] + qkv[base+QKVS] + qkv[base+2*QKVS] + qkv[base+3*QKVS]);
}

// ---------------- fused NSA attention, split-n, dense kc/vc layout ----------------
// grid = 1024 blocks: block e -> token group g = 31 - e/32 (heavy first), (b,h) = e%32.
// Wave w computes compressed-branch partials over n-quarter [w*chunk,(w+1)*chunk);
// partials combine in LDS (max-free softmax is linear); wave w finalizes tokens
// [16w,16w+16) (selection + sliding window + gated store).
__global__ __launch_bounds__(256, 4) void nsa_attn(
    const float* __restrict__ qkv, const float* __restrict__ kc, const float* __restrict__ vc,
    float* __restrict__ o)
{
  __shared__ float red[4*64*36];   // 36 KiB
  int e = blockIdx.x;
  int gidx = 31 - (e >> 5);        // token group, heavy groups dispatched first
  int bh = e & 31;
  int hh = bh & 7, b = bh >> 3;
  int tid = threadIdx.x;
  int w = __builtin_amdgcn_readfirstlane(tid >> 6);
  int lane = tid & 63;
  int t = gidx*64 + lane;
  const float* kcg = kc + ((size_t)(b*NH + hh)*NB)*DH;
  const float* vcg = vc + ((size_t)(b*NH + hh)*NB)*DH;

  size_t rowq = ((size_t)b*SEQ + t)*QKVS + hh*DH;
  float qv[32];
  #pragma unroll
  for (int d=0; d<32; d+=4){
    float4 t4 = *(const float4*)(qkv + rowq + d);
    qv[d]=t4.x; qv[d+1]=t4.y; qv[d+2]=t4.z; qv[d+3]=t4.w;
  }
  int own = t >> 2, nvis = (t+1) >> 2;

  // ---- phase 1: compressed-branch partial over this wave's n-quarter
  int chunk = 4*(gidx+1);
  int n0 = w*chunk, n1 = n0 + chunk;
  float l = 0.f, best = -1e30f;
  int bestn = -1;
  float acc[32];
  #pragma unroll
  for (int d=0;d<32;d++) acc[d]=0.f;
  for (int n=n0; n<n1; ++n){
    const float* kp = kcg + (size_t)n*DH;    // wave-uniform, dense 128B row
    float s = 0.f;
    #pragma unroll
    for (int d=0; d<32; d+=4){
      float4 kv = *(const float4*)(kp + d);
      s += qv[d]*kv.x + qv[d+1]*kv.y + qv[d+2]*kv.z + qv[d+3]*kv.w;
    }
    s *= SCALE;
    bool act = (n < nvis);
    if (act && n != own && s > best){ best = s; bestn = n; }  // strict > = lowest-index tie-break
    float p = act ? __expf(s) : 0.f;          // max-free: |s| small, exp safe
    l += p;
    const float* vp = vcg + (size_t)n*DH;
    #pragma unroll
    for (int d=0; d<32; d+=4){
      float4 vv = *(const float4*)(vp + d);
      acc[d]   += p*vv.x; acc[d+1] += p*vv.y;
      acc[d+2] += p*vv.z; acc[d+3] += p*vv.w;
    }
  }
  float4* myr = (float4*)&red[(w*64 + lane)*36];
  #pragma unroll
  for (int d=0; d<8; d++) myr[d] = make_float4(acc[d*4],acc[d*4+1],acc[d*4+2],acc[d*4+3]);
  myr[8] = make_float4(l, best, __int_as_float(bestn), 0.f);
  __syncthreads();

  // ---- phase 2: wave w finalizes tokens [16w, 16w+16)
  if ((lane >> 4) != w) return;

  float ll = 0.f, bb = -1e30f;
  int bn = (own==0) ? 1 : 0;       // jax top_k fallback when no visible non-own block
  float out[32];
  #pragma unroll
  for (int d=0;d<32;d++) out[d]=0.f;
  #pragma unroll
  for (int sp=0; sp<4; ++sp){      // ascending split = ascending n: tie-break preserved
    const float4* r = (const float4*)&red[(sp*64 + lane)*36];
    #pragma unroll
    for (int d=0; d<8; d++){
      float4 a4 = r[d];
      out[d*4]+=a4.x; out[d*4+1]+=a4.y; out[d*4+2]+=a4.z; out[d*4+3]+=a4.w;
    }
    float4 m4 = r[8];
    ll += m4.x;
    if (m4.y > bb){ bb = m4.y; bn = __float_as_int(m4.z); }
  }
  const float* gr = qkv + ((size_t)b*SEQ + t)*QKVS + 768;
  float g0 = sigmoidf_(gr[hh]), g1 = sigmoidf_(gr[8+hh]), g2 = sigmoidf_(gr[16+hh]);
  float inv = (nvis > 0) ? g0/ll : 0.f;
  #pragma unroll
  for (int d=0;d<32;d++) out[d] *= inv;

  // ---- selection branch: own block + best block, causal token mask
  const float* kbase = qkv + (size_t)b*SEQ*QKVS + 256 + hh*DH;
  const float* vbase = kbase + 256;
  float s2[8];
  float m2 = -1e30f;
  #pragma unroll
  for (int ki=0; ki<8; ++ki){
    int tt = (ki<4 ? own : bn)*4 + (ki&3);
    float s = -1e30f;
    if (tt <= t){
      const float* kr = kbase + (size_t)tt*QKVS;
      float sv = 0.f;
      #pragma unroll
      for (int d=0; d<32; d+=4){
        float4 kv = *(const float4*)(kr + d);
        sv += qv[d]*kv.x + qv[d+1]*kv.y + qv[d+2]*kv.z + qv[d+3]*kv.w;
      }
      s = sv*SCALE;
      m2 = fmaxf(m2, s);
    }
    s2[ki] = s;
  }
  float l2 = 0.f;
  #pragma unroll
  for (int ki=0; ki<8; ++ki)
    if (s2[ki] > -1e29f) l2 += __expf(s2[ki] - m2);
  float inv2 = g1/l2;              // l2 >= 1 (self token always visible)
  #pragma unroll
  for (int ki=0; ki<8; ++ki){
    int tt = (ki<4 ? own : bn)*4 + (ki&3);
    if (tt <= t){
      float pw = __expf(s2[ki] - m2) * inv2;
      const float* vr = vbase + (size_t)tt*QKVS;
      #pragma unroll
      for (int d=0; d<32; d+=4){
        float4 vv = *(const float4*)(vr + d);
        out[d]   += pw*vv.x; out[d+1] += pw*vv.y;
        out[d+2] += pw*vv.z; out[d+3] += pw*vv.w;
      }
    }
  }

  // ---- sliding window (W=2): tokens t-1, t
  int tp = (t>0) ? t-1 : 0;
  const float* ka = kbase + (size_t)tp*QKVS;
  const float* kb2= kbase + (size_t)t *QKVS;
  float sa=0.f, sb=0.f;
  #pragma unroll
  for (int d=0; d<32; d+=4){
    float4 k1 = *(const float4*)(ka + d);
    float4 k2 = *(const float4*)(kb2 + d);
    sa += qv[d]*k1.x + qv[d+1]*k1.y + qv[d+2]*k1.z + qv[d+3]*k1.w;
    sb += qv[d]*k2.x + qv[d+1]*k2.y + qv[d+2]*k2.z + qv[d+3]*k2.w;
  }
  sa *= SCALE; sb *= SCALE;
  float m3 = (t>0) ? fmaxf(sa, sb) : sb;
  float pa = (t>0) ? __expf(sa-m3) : 0.f;
  float pb = __expf(sb-m3);
  float inv3 = g2/(pa+pb);
  const float* va = vbase + (size_t)tp*QKVS;
  const float* vb = vbase + (size_t)t *QKVS;
  float* orow = o + ((size_t)b*SEQ + t)*DIM + hh*DH;
  #pragma unroll
  for (int d=0; d<32; d+=4){
    float4 a4 = *(const float4*)(va+d);
    float4 b4 = *(const float4*)(vb+d);
    float4 r;
    r.x = out[d]   + (pa*a4.x + pb*b4.x)*inv3;
    r.y = out[d+1] + (pa*a4.y + pb*b4.y)*inv3;
    r.z = out[d+2] + (pa*a4.z + pb*b4.z)*inv3;
    r.w = out[d+3] + (pa*a4.w + pb*b4.w)*inv3;
    *(float4*)(orow+d) = r;
  }
}

extern "C" void kernel_launch(void* const* d_in, const int* in_sizes, int n_in,
                              void* d_out, int out_size, void* d_ws, size_t ws_size,
                              hipStream_t stream) {
  const float* x_in   = (const float*)d_in[0];
  const float* ln_a_g = (const float*)d_in[1];
  const float* ln_a_b = (const float*)d_in[2];
  const float* Wq     = (const float*)d_in[3];
  const float* Wk     = (const float*)d_in[4];
  const float* Wv     = (const float*)d_in[5];
  const float* Wg     = (const float*)d_in[6];
  const float* Wo     = (const float*)d_in[7];
  const float* ln_f_g = (const float*)d_in[8];
  const float* ln_f_b = (const float*)d_in[9];
  const float* W1     = (const float*)d_in[10];
  const float* b1     = (const float*)d_in[11];
  const float* W2     = (const float*)d_in[12];
  const float* b2     = (const float*)d_in[13];

  float* xout = (float*)d_out;             // running residual stream [8192][256]
  float* ws = (float*)d_ws;
  const size_t NTOK = (size_t)BATCH*SEQ;   // 8192
  float* h    = ws;                              // [8192][256]
  float* qkv  = h    + NTOK*DIM;                 // [8192][832]
  float* wcat = qkv  + NTOK*QKVS;                // [4][256][832]
  float* kcb  = wcat + (size_t)4*DIM*QKVS;       // [4][8][512][32]
  float* vcb  = kcb  + (size_t)BATCH*NH*NB*DH;
  float* ob   = vcb  + (size_t)BATCH*NH*NB*DH;   // [8192][256]
  float* mid  = ob   + NTOK*DIM;                 // [8192][512]

  copy_f32<<<2048, 256, 0, stream>>>(x_in, xout, (int)(NTOK*DIM/4));
  build_wcat<<<(4*256*QKVS+255)/256, 256, 0, stream>>>(Wq, Wk, Wv, Wg, wcat);

  dim3 gq(64,13), g4(64,4), g8(64,8);
  for (int i=0;i<4;i++){
    ln_k<<<2048,256,0,stream>>>(xout, ln_a_g + i*DIM, ln_a_b + i*DIM, h);
    gemm_f32<false,false,false><<<gq,256,0,stream>>>(h, wcat + (size_t)i*DIM*QKVS, nullptr, qkv, 8192,QKVS,256);
    pool_k<<<2048,256,0,stream>>>(qkv, kcb, vcb);
    nsa_attn<<<1024,256,0,stream>>>(qkv, kcb, vcb, ob);
    gemm_f32<false,false,true><<<g4,256,0,stream>>>(ob, Wo + (size_t)i*DIM*DIM, nullptr, xout, 8192,256,256);
    if (i & 1){
      int l = i >> 1;
      ln_k<<<2048,256,0,stream>>>(xout, ln_f_g + l*DIM, ln_f_b + l*DIM, h);
      gemm_f32<true,true,false><<<g8,256,0,stream>>>(h,   W1 + (size_t)l*DIM*512, b1 + l*512, mid,  8192,512,256);
      gemm_f32<true,false,true><<<g4,256,0,stream>>>(mid, W2 + (size_t)l*512*DIM, b2 + l*DIM, xout, 8192,256,512);
    }
  }
}

// Round 4
// 635.987 us; speedup vs baseline: 2.4630x; 1.4204x over previous
//
#include <hip/hip_runtime.h>
#include <hip/hip_bf16.h>
#include <math.h>

#define NH 8
#define DH 32
#define DIM 256
#define SEQ 2048
#define BATCH 4
#define NB 512            // SEQ / C
#define QKS 512           // q|k packed f32 row stride
#define VGS 320           // v|g packed bf16 row stride: 256 v | 24 g | 40 pad
#define SCALE 0.17677669529663687f  // DH^-0.5

typedef short short8v __attribute__((ext_vector_type(8)));
typedef float float4v __attribute__((ext_vector_type(4)));

__device__ __forceinline__ float sigmoidf_(float x){ return 1.f/(1.f+__expf(-x)); }
__device__ __forceinline__ ushort f2bf(float f){
  uint b = __float_as_uint(f);
  return (ushort)((b + 0x7fffu + ((b>>16)&1u)) >> 16);   // RNE
}
__device__ __forceinline__ float bf2f(ushort u){ return __uint_as_float(((uint)u)<<16); }
__device__ __forceinline__ void bf8_to_f32(const ushort* p, float* f){
  uint4 u = *(const uint4*)p;
  f[0]=__uint_as_float(u.x<<16); f[1]=__uint_as_float(u.x&0xffff0000u);
  f[2]=__uint_as_float(u.y<<16); f[3]=__uint_as_float(u.y&0xffff0000u);
  f[4]=__uint_as_float(u.z<<16); f[5]=__uint_as_float(u.z&0xffff0000u);
  f[6]=__uint_as_float(u.w<<16); f[7]=__uint_as_float(u.w&0xffff0000u);
}

// ---------------- copy (residual stream init) ----------------
__global__ void copy_f32(const float* __restrict__ in, float* __restrict__ out, int n4){
  int i = blockIdx.x*blockDim.x + threadIdx.x;
  if (i < n4) ((float4*)out)[i] = ((const float4*)in)[i];
}

// ---------------- weight packers ----------------
__global__ void build_wqk(const float* __restrict__ Wq, const float* __restrict__ Wk, float* __restrict__ out){
  int i = blockIdx.x*256 + threadIdx.x;          // 4*256*512
  if (i >= 4*256*QKS) return;
  int col = i & 511, rk = (i>>9)&255, l = i>>17;
  out[i] = (col < 256) ? Wq[((size_t)l*256+rk)*256+col] : Wk[((size_t)l*256+rk)*256+col-256];
}
__global__ void build_wvgT(const float* __restrict__ Wv, const float* __restrict__ Wg, ushort* __restrict__ out){
  int i = blockIdx.x*256 + threadIdx.x;          // 4*320*256 : out[l][n][k] = B[k][n]
  if (i >= 4*VGS*256) return;
  int k = i & 255, n = (i>>8)%VGS, l = i/(VGS*256);
  float v = 0.f;
  if      (n < 256) v = Wv[((size_t)l*256+k)*256+n];
  else if (n < 280) v = Wg[((size_t)l*256+k)*24 + (n-256)];
  out[i] = f2bf(v);
}
__global__ void build_wT(const float* __restrict__ in, ushort* __restrict__ out, int L, int K, int N){
  int i = blockIdx.x*256 + threadIdx.x;          // out[l][n][k] = in[l][k][n]
  if (i >= L*K*N) return;
  int k = i % K, n = (i/K) % N, l = i/(K*N);
  out[i] = f2bf(in[((size_t)l*K+k)*N+n]);
}

// ---------------- layernorm: one wave per row, dual f32+bf16 output ----------------
__global__ __launch_bounds__(256) void ln_k(const float* __restrict__ x, const float* __restrict__ g,
                                            const float* __restrict__ b, float* __restrict__ h,
                                            ushort* __restrict__ hb){
  int row  = blockIdx.x*4 + (threadIdx.x>>6);
  int lane = threadIdx.x & 63;
  int c = lane*4;
  const float* xr = x + (size_t)row*DIM + c;
  float4 v = *(const float4*)xr;
  float s = v.x+v.y+v.z+v.w;
  float q = v.x*v.x+v.y*v.y+v.z*v.z+v.w*v.w;
  #pragma unroll
  for (int off=32; off>0; off>>=1){ s += __shfl_xor(s, off); q += __shfl_xor(q, off); }
  float mean = s * (1.f/DIM);
  float var  = q * (1.f/DIM) - mean*mean;
  float rs = rsqrtf(var + 1e-5f);
  float4 gg = *(const float4*)(g + c);
  float4 bb = *(const float4*)(b + c);
  float4 o;
  o.x = (v.x-mean)*rs*gg.x + bb.x;
  o.y = (v.y-mean)*rs*gg.y + bb.y;
  o.z = (v.z-mean)*rs*gg.z + bb.z;
  o.w = (v.w-mean)*rs*gg.w + bb.w;
  *(float4*)(h + (size_t)row*DIM + c) = o;
  uint2 u;
  u.x = (uint)f2bf(o.x) | ((uint)f2bf(o.y)<<16);
  u.y = (uint)f2bf(o.z) | ((uint)f2bf(o.w)<<16);
  *(uint2*)&hb[(size_t)row*DIM + c] = u;
}

// ---------------- f32 GEMM (q|k path), guard-free ----------------
template<bool BIAS, bool LEAKY, bool ACC>
__global__ __launch_bounds__(256) void gemm_f32(const float* __restrict__ A, const float* __restrict__ B,
                                                const float* __restrict__ bias, float* __restrict__ C,
                                                int M, int N, int K){
  __shared__ float As[16][132];
  __shared__ float Bs[16][68];
  int tid = threadIdx.x;
  int m0 = blockIdx.x*128, n0 = blockIdx.y*64;
  int tx = tid & 15, ty = tid >> 4;
  int ar = tid >> 2;
  int ac = (tid & 3)*4;
  int bk = tid >> 4;
  int bn = (tid & 15)*4;
  const float* Ap0 = A + (size_t)(m0+ar)*K + ac;
  const float* Ap1 = Ap0 + (size_t)64*K;
  const float* Bp  = B + (size_t)bk*N + n0 + bn;
  float4 a0 = *(const float4*)Ap0;
  float4 a1 = *(const float4*)Ap1;
  float4 b0 = *(const float4*)Bp;
  float acc[8][4];
  #pragma unroll
  for (int i=0;i<8;i++)
    #pragma unroll
    for (int j=0;j<4;j++) acc[i][j]=0.f;
  for (int k0=0; k0<K; k0+=16){
    As[ac+0][ar]=a0.x; As[ac+1][ar]=a0.y; As[ac+2][ar]=a0.z; As[ac+3][ar]=a0.w;
    As[ac+0][ar+64]=a1.x; As[ac+1][ar+64]=a1.y; As[ac+2][ar+64]=a1.z; As[ac+3][ar+64]=a1.w;
    *(float4*)&Bs[bk][bn] = b0;
    __syncthreads();
    if (k0 + 16 < K){
      a0 = *(const float4*)(Ap0 + k0 + 16);
      a1 = *(const float4*)(Ap1 + k0 + 16);
      b0 = *(const float4*)(Bp + (size_t)(k0+16)*N);
    }
    #pragma unroll
    for (int kk=0;kk<16;kk++){
      float4 bv  = *(const float4*)&Bs[kk][tx*4];
      float4 av0 = *(const float4*)&As[kk][ty*8];
      float4 av1 = *(const float4*)&As[kk][ty*8+4];
      float av[8] = {av0.x,av0.y,av0.z,av0.w,av1.x,av1.y,av1.z,av1.w};
      float bw[4] = {bv.x,bv.y,bv.z,bv.w};
      #pragma unroll
      for (int i=0;i<8;i++)
        #pragma unroll
        for (int j=0;j<4;j++) acc[i][j] += av[i]*bw[j];
    }
    __syncthreads();
  }
  #pragma unroll
  for (int i=0;i<8;i++){
    int m = m0 + ty*8 + i;
    #pragma unroll
    for (int j=0;j<4;j++){
      int n = n0 + tx*4 + j;
      float val = acc[i][j];
      if (BIAS)  val += bias[n];
      if (LEAKY) val = val > 0.f ? val : 0.01f*val;
      float* cp = C + (size_t)m*N + n;
      if (ACC) val += *cp;
      *cp = val;
    }
  }
}

// ---------------- bf16 MFMA GEMM: C = act(A[M,K] @ Bt[N,K]^T + bias) ----------------
// tile 128x64, BK=64, 4 waves (2x2), per-wave 64x32 = 4x2 16x16 frags.
// LDS XOR-swizzled on 16B k-chunks; A/B loaders share the k-mapping so any
// HW k-permutation self-cancels; C/D layout col=lane&15,row=(lane>>4)*4+reg (verified).
template<bool BIAS, bool LEAKY, bool ACC, bool OBF16>
__global__ __launch_bounds__(256) void gemm_bf16(const ushort* __restrict__ A, const ushort* __restrict__ Bt,
                                                 const float* __restrict__ bias, void* __restrict__ Cv,
                                                 int M, int N, int K){
  __shared__ ushort Al[128*64];
  __shared__ ushort Bl[64*64];
  int tid = threadIdx.x;
  int m0 = blockIdx.x*128, n0 = blockIdx.y*64;
  int w = tid>>6, lane = tid&63;
  int wm = w>>1, wn = w&1;
  float4v acc[4][2];
  #pragma unroll
  for (int i=0;i<4;i++)
    #pragma unroll
    for (int j=0;j<2;j++) acc[i][j] = (float4v){0.f,0.f,0.f,0.f};
  for (int k0=0; k0<K; k0+=64){
    #pragma unroll
    for (int i=0;i<4;i++){
      int id = tid + 256*i;
      int r = id>>3, c = id&7;
      *(uint4*)&Al[r*64 + ((c ^ (r&7))*8)] = *(const uint4*)&A[(size_t)(m0+r)*K + k0 + c*8];
    }
    #pragma unroll
    for (int i=0;i<2;i++){
      int id = tid + 256*i;
      int r = id>>3, c = id&7;
      *(uint4*)&Bl[r*64 + ((c ^ (r&7))*8)] = *(const uint4*)&Bt[(size_t)(n0+r)*K + k0 + c*8];
    }
    __syncthreads();
    #pragma unroll
    for (int kk=0; kk<2; ++kk){
      short8v a[4], bfr[2];
      #pragma unroll
      for (int mf=0; mf<4; mf++){
        int r = wm*64 + mf*16 + (lane&15);
        int c = (kk*4 + (lane>>4)) ^ (r&7);
        a[mf] = *(short8v*)&Al[r*64 + c*8];
      }
      #pragma unroll
      for (int nf=0; nf<2; nf++){
        int r = wn*32 + nf*16 + (lane&15);
        int c = (kk*4 + (lane>>4)) ^ (r&7);
        bfr[nf] = *(short8v*)&Bl[r*64 + c*8];
      }
      #pragma unroll
      for (int mf=0; mf<4; mf++)
        #pragma unroll
        for (int nf=0; nf<2; nf++)
          acc[mf][nf] = __builtin_amdgcn_mfma_f32_16x16x32_bf16(a[mf], bfr[nf], acc[mf][nf], 0, 0, 0);
    }
    __syncthreads();
  }
  #pragma unroll
  for (int nf=0; nf<2; nf++){
    int col = n0 + wn*32 + nf*16 + (lane&15);
    float bv = BIAS ? bias[col] : 0.f;
    #pragma unroll
    for (int mf=0; mf<4; mf++){
      #pragma unroll
      for (int r=0; r<4; r++){
        int row = m0 + wm*64 + mf*16 + (lane>>4)*4 + r;
        float vv = acc[mf][nf][r];
        if (BIAS) vv += bv;
        if (LEAKY) vv = vv > 0.f ? vv : 0.01f*vv;
        if (OBF16) ((ushort*)Cv)[(size_t)row*N + col] = f2bf(vv);
        else {
          float* C = (float*)Cv;
          if (ACC) vv += C[(size_t)row*N + col];
          C[(size_t)row*N + col] = vv;
        }
      }
    }
  }
}

// ---------------- mean-pool K/V blocks (C=4), output [b][h][n][32] f32 ----------------
__global__ void pool_k(const float* __restrict__ qk, const ushort* __restrict__ vg,
                       float* __restrict__ kc, float* __restrict__ vc){
  int i = blockIdx.x*256 + threadIdx.x;       // 0 .. B*H*NB*32-1
  if (i >= BATCH*NH*NB*DH) return;
  int d = i & 31, n = (i >> 5) & 511, h = (i >> 14) & 7, b = i >> 17;
  size_t kb = ((size_t)(b*SEQ + n*4))*QKS + 256 + h*DH + d;
  kc[i] = 0.25f*(qk[kb] + qk[kb+QKS] + qk[kb+2*QKS] + qk[kb+3*QKS]);
  size_t vb = ((size_t)(b*SEQ + n*4))*VGS + h*DH + d;
  vc[i] = 0.25f*(bf2f(vg[vb]) + bf2f(vg[vb+VGS]) + bf2f(vg[vb+2*VGS]) + bf2f(vg[vb+3*VGS]));
}

// ---------------- fused NSA attention, split-n, XCD-local ----------------
// decode: slot=e&7 (XCD), j2=e>>3: gidx = 31-(j2>>2) (heavy first), bh = slot + 8*(j2&3).
// All 32 token-groups of one (b,h) share an XCD -> kc/vc (128KB) L2-resident.
__global__ __launch_bounds__(256, 3) void nsa_attn(
    const float* __restrict__ qk, const ushort* __restrict__ vg,
    const float* __restrict__ kc, const float* __restrict__ vc,
    ushort* __restrict__ o)
{
  __shared__ float red[4*64*36];   // 36 KiB
  int e = blockIdx.x;
  int j2 = e >> 3;
  int gidx = 31 - (j2 >> 2);
  int bh = (e & 7) + ((j2 & 3) << 3);
  int hh = bh & 7, b = bh >> 3;
  int tid = threadIdx.x;
  int w = __builtin_amdgcn_readfirstlane(tid >> 6);
  int lane = tid & 63;
  int t = gidx*64 + lane;
  const float* kcg = kc + ((size_t)(b*NH + hh)*NB)*DH;
  const float* vcg = vc + ((size_t)(b*NH + hh)*NB)*DH;

  size_t rowq = ((size_t)b*SEQ + t)*QKS + hh*DH;
  float qv[32];
  #pragma unroll
  for (int d=0; d<32; d+=4){
    float4 t4 = *(const float4*)(qk + rowq + d);
    qv[d]=t4.x; qv[d+1]=t4.y; qv[d+2]=t4.z; qv[d+3]=t4.w;
  }
  int own = t >> 2, nvis = (t+1) >> 2;

  // ---- phase 1: compressed-branch partial, 2x unrolled for load run-ahead
  int chunk = 4*(gidx+1);
  int n0 = w*chunk, n1 = n0 + chunk;
  float l = 0.f, best = -1e30f;
  int bestn = -1;
  float acc[32];
  #pragma unroll
  for (int d=0;d<32;d++) acc[d]=0.f;
  for (int n=n0; n<n1; n+=2){
    const float4* kp0 = (const float4*)(kcg + (size_t)n*DH);
    const float4* kp1 = (const float4*)(kcg + (size_t)(n+1)*DH);
    float k0v[32], k1v[32];
    #pragma unroll
    for (int d=0; d<8; d++){
      float4 t0 = kp0[d], t1 = kp1[d];
      k0v[4*d]=t0.x; k0v[4*d+1]=t0.y; k0v[4*d+2]=t0.z; k0v[4*d+3]=t0.w;
      k1v[4*d]=t1.x; k1v[4*d+1]=t1.y; k1v[4*d+2]=t1.z; k1v[4*d+3]=t1.w;
    }
    float s0=0.f, s1=0.f;
    #pragma unroll
    for (int d=0; d<32; d++){ s0 += qv[d]*k0v[d]; s1 += qv[d]*k1v[d]; }
    s0 *= SCALE; s1 *= SCALE;
    bool a0 = (n < nvis), a1 = (n+1 < nvis);
    if (a0 && n   != own && s0 > best){ best = s0; bestn = n;   }
    if (a1 && n+1 != own && s1 > best){ best = s1; bestn = n+1; }
    float p0 = a0 ? __expf(s0) : 0.f;
    float p1 = a1 ? __expf(s1) : 0.f;
    l += p0 + p1;
    const float4* vp0 = (const float4*)(vcg + (size_t)n*DH);
    const float4* vp1 = (const float4*)(vcg + (size_t)(n+1)*DH);
    #pragma unroll
    for (int d=0; d<8; d++){
      float4 v0 = vp0[d], v1 = vp1[d];
      acc[4*d]   += p0*v0.x + p1*v1.x;
      acc[4*d+1] += p0*v0.y + p1*v1.y;
      acc[4*d+2] += p0*v0.z + p1*v1.z;
      acc[4*d+3] += p0*v0.w + p1*v1.w;
    }
  }
  float4* myr = (float4*)&red[(w*64 + lane)*36];
  #pragma unroll
  for (int d=0; d<8; d++) myr[d] = make_float4(acc[d*4],acc[d*4+1],acc[d*4+2],acc[d*4+3]);
  myr[8] = make_float4(l, best, __int_as_float(bestn), 0.f);
  __syncthreads();

  // ---- phase 2: wave w finalizes tokens [16w, 16w+16)
  if ((lane >> 4) != w) return;

  float ll = 0.f, bb = -1e30f;
  int bn = (own==0) ? 1 : 0;       // jax top_k fallback when no visible non-own block
  float out[32];
  #pragma unroll
  for (int d=0;d<32;d++) out[d]=0.f;
  #pragma unroll
  for (int sp=0; sp<4; ++sp){      // ascending split = ascending n: tie-break preserved
    const float4* r = (const float4*)&red[(sp*64 + lane)*36];
    #pragma unroll
    for (int d=0; d<8; d++){
      float4 a4 = r[d];
      out[d*4]+=a4.x; out[d*4+1]+=a4.y; out[d*4+2]+=a4.z; out[d*4+3]+=a4.w;
    }
    float4 m4 = r[8];
    ll += m4.x;
    if (m4.y > bb){ bb = m4.y; bn = __float_as_int(m4.z); }
  }
  const ushort* gr = vg + ((size_t)b*SEQ + t)*VGS + 256;
  float g0 = sigmoidf_(bf2f(gr[hh])), g1 = sigmoidf_(bf2f(gr[8+hh])), g2 = sigmoidf_(bf2f(gr[16+hh]));
  float inv = (nvis > 0) ? g0/ll : 0.f;
  #pragma unroll
  for (int d=0;d<32;d++) out[d] *= inv;

  // ---- selection branch: own block + best block, causal token mask
  const float*  kbase = qk + (size_t)b*SEQ*QKS + 256 + hh*DH;
  const ushort* vbase = vg + (size_t)b*SEQ*VGS + hh*DH;
  float s2[8];
  float m2 = -1e30f;
  #pragma unroll
  for (int ki=0; ki<8; ++ki){
    int tt = (ki<4 ? own : bn)*4 + (ki&3);
    float s = -1e30f;
    if (tt <= t){
      const float* kr = kbase + (size_t)tt*QKS;
      float sv = 0.f;
      #pragma unroll
      for (int d=0; d<32; d+=4){
        float4 kv = *(const float4*)(kr + d);
        sv += qv[d]*kv.x + qv[d+1]*kv.y + qv[d+2]*kv.z + qv[d+3]*kv.w;
      }
      s = sv*SCALE;
      m2 = fmaxf(m2, s);
    }
    s2[ki] = s;
  }
  float l2 = 0.f;
  #pragma unroll
  for (int ki=0; ki<8; ++ki)
    if (s2[ki] > -1e29f) l2 += __expf(s2[ki] - m2);
  float inv2 = g1/l2;              // l2 >= 1 (self token always visible)
  #pragma unroll
  for (int ki=0; ki<8; ++ki){
    int tt = (ki<4 ? own : bn)*4 + (ki&3);
    if (tt <= t){
      float pw = __expf(s2[ki] - m2) * inv2;
      float vvv[32];
      #pragma unroll
      for (int d=0; d<32; d+=8) bf8_to_f32(vbase + (size_t)tt*VGS + d, &vvv[d]);
      #pragma unroll
      for (int d=0; d<32; d++) out[d] += pw*vvv[d];
    }
  }

  // ---- sliding window (W=2): tokens t-1, t
  int tp = (t>0) ? t-1 : 0;
  const float* ka = kbase + (size_t)tp*QKS;
  const float* kb2= kbase + (size_t)t *QKS;
  float sa=0.f, sb=0.f;
  #pragma unroll
  for (int d=0; d<32; d+=4){
    float4 k1 = *(const float4*)(ka + d);
    float4 k2 = *(const float4*)(kb2 + d);
    sa += qv[d]*k1.x + qv[d+1]*k1.y + qv[d+2]*k1.z + qv[d+3]*k1.w;
    sb += qv[d]*k2.x + qv[d+1]*k2.y + qv[d+2]*k2.z + qv[d+3]*k2.w;
  }
  sa *= SCALE; sb *= SCALE;
  float m3 = (t>0) ? fmaxf(sa, sb) : sb;
  float pa = (t>0) ? __expf(sa-m3) : 0.f;
  float pb = __expf(sb-m3);
  float inv3 = g2/(pa+pb);
  float va[32], vbv[32];
  #pragma unroll
  for (int d=0; d<32; d+=8){
    bf8_to_f32(vbase + (size_t)tp*VGS + d, &va[d]);
    bf8_to_f32(vbase + (size_t)t *VGS + d, &vbv[d]);
  }
  ushort* orow = o + ((size_t)b*SEQ + t)*DIM + hh*DH;
  #pragma unroll
  for (int d=0; d<32; d+=8){
    float r0[8];
    #pragma unroll
    for (int j=0;j<8;j++) r0[j] = out[d+j] + (pa*va[d+j] + pb*vbv[d+j])*inv3;
    uint4 u;
    u.x = (uint)f2bf(r0[0]) | ((uint)f2bf(r0[1])<<16);
    u.y = (uint)f2bf(r0[2]) | ((uint)f2bf(r0[3])<<16);
    u.z = (uint)f2bf(r0[4]) | ((uint)f2bf(r0[5])<<16);
    u.w = (uint)f2bf(r0[6]) | ((uint)f2bf(r0[7])<<16);
    *(uint4*)&orow[d] = u;
  }
}

extern "C" void kernel_launch(void* const* d_in, const int* in_sizes, int n_in,
                              void* d_out, int out_size, void* d_ws, size_t ws_size,
                              hipStream_t stream) {
  const float* x_in   = (const float*)d_in[0];
  const float* ln_a_g = (const float*)d_in[1];
  const float* ln_a_b = (const float*)d_in[2];
  const float* Wq     = (const float*)d_in[3];
  const float* Wk     = (const float*)d_in[4];
  const float* Wv     = (const float*)d_in[5];
  const float* Wg     = (const float*)d_in[6];
  const float* Wo     = (const float*)d_in[7];
  const float* ln_f_g = (const float*)d_in[8];
  const float* ln_f_b = (const float*)d_in[9];
  const float* W1     = (const float*)d_in[10];
  const float* b1     = (const float*)d_in[11];
  const float* W2     = (const float*)d_in[12];
  const float* b2     = (const float*)d_in[13];

  float* xout = (float*)d_out;             // running residual stream [8192][256] f32
  float* ws = (float*)d_ws;
  const size_t NTOK = (size_t)BATCH*SEQ;   // 8192
  float* h    = ws;                                    // [8192][256] f32
  float* qkb  = h    + NTOK*DIM;                       // [8192][512] f32
  float* kcb  = qkb  + NTOK*QKS;                       // [4][8][512][32] f32
  float* vcb  = kcb  + (size_t)BATCH*NH*NB*DH;
  float* wqk  = vcb  + (size_t)BATCH*NH*NB*DH;         // [4][256][512] f32
  ushort* hb   = (ushort*)(wqk + (size_t)4*DIM*QKS);   // [8192][256] bf16
  ushort* vgu  = hb   + NTOK*DIM;                      // [8192][320] bf16
  ushort* obu  = vgu  + NTOK*VGS;                      // [8192][256] bf16
  ushort* midu = obu  + NTOK*DIM;                      // [8192][512] bf16
  ushort* wvgT = midu + NTOK*512;                      // [4][320][256] bf16
  ushort* woT  = wvgT + (size_t)4*VGS*DIM;             // [4][256][256] bf16
  ushort* w1T  = woT  + (size_t)4*DIM*DIM;             // [2][512][256] bf16
  ushort* w2T  = w1T  + (size_t)2*512*DIM;             // [2][256][512] bf16

  copy_f32<<<2048, 256, 0, stream>>>(x_in, xout, (int)(NTOK*DIM/4));
  build_wqk <<<(4*256*QKS+255)/256, 256, 0, stream>>>(Wq, Wk, wqk);
  build_wvgT<<<(4*VGS*256+255)/256, 256, 0, stream>>>(Wv, Wg, wvgT);
  build_wT  <<<(4*256*256+255)/256, 256, 0, stream>>>(Wo, woT, 4, 256, 256);
  build_wT  <<<(2*256*512+255)/256, 256, 0, stream>>>(W1, w1T, 2, 256, 512);
  build_wT  <<<(2*512*256+255)/256, 256, 0, stream>>>(W2, w2T, 2, 512, 256);

  dim3 gqk(64,8), gvg(64,5), g4(64,4), g8(64,8);
  for (int i=0;i<4;i++){
    ln_k<<<2048,256,0,stream>>>(xout, ln_a_g + i*DIM, ln_a_b + i*DIM, h, hb);
    gemm_f32<false,false,false><<<gqk,256,0,stream>>>(h, wqk + (size_t)i*DIM*QKS, nullptr, qkb, 8192,QKS,256);
    gemm_bf16<false,false,false,true><<<gvg,256,0,stream>>>(hb, wvgT + (size_t)i*VGS*DIM, nullptr, vgu, 8192,VGS,256);
    pool_k<<<2048,256,0,stream>>>(qkb, vgu, kcb, vcb);
    nsa_attn<<<1024,256,0,stream>>>(qkb, vgu, kcb, vcb, obu);
    gemm_bf16<false,false,true,false><<<g4,256,0,stream>>>(obu, woT + (size_t)i*DIM*DIM, nullptr, xout, 8192,DIM,256);
    if (i & 1){
      int l = i >> 1;
      ln_k<<<2048,256,0,stream>>>(xout, ln_f_g + l*DIM, ln_f_b + l*DIM, h, hb);
      gemm_bf16<true,true,false,true><<<g8,256,0,stream>>>(hb,   w1T + (size_t)l*512*DIM, b1 + l*512, midu, 8192,512,256);
      gemm_bf16<true,false,true,false><<<g4,256,0,stream>>>(midu, w2T + (size_t)l*DIM*512, b2 + l*DIM, xout, 8192,DIM,512);
    }
  }
}